// Round 3
// baseline (481.247 us; speedup 1.0000x reference)
//
#include <hip/hip_runtime.h>
#include <hip/hip_bf16.h>
#include <stdint.h>

typedef __attribute__((ext_vector_type(8))) short bf16x8;
typedef __attribute__((ext_vector_type(4))) short bf16x4;
typedef __attribute__((ext_vector_type(4))) float f32x4;

__device__ __forceinline__ float b2f(short s) {
  union { unsigned u; float f; } cv;
  cv.u = ((unsigned)(unsigned short)s) << 16;
  return cv.f;
}
__device__ __forceinline__ short f2b(float f) {
  __hip_bfloat16 h = __float2bfloat16(f);
  return *reinterpret_cast<short*>(&h);
}

// Layouts:
//  xT[b][t][c] bf16 (c contiguous, 512/row), per-level elem offsets {0, 8388608, 12582912}.
//  W frags (k-major r = k*512+c): fid = mb*48+kt, lane l: o = mb*16+(l&15), r = kt*32+(l>>4)*8+j.
//  owF1 frags (j-major rr = j*512+c): fid = kt (0..47), lane l: k = l&15 (rows>=3 zero),
//    rr = kt*32+(l>>4)*8+j; stored twice: hi = bf16(v), lo = bf16(v - hi).

// ---------- setup: pack W0/W1 frags, owF1 hi/lo frags, mask outputs ----------
__global__ __launch_bounds__(256) void setup_kernel(
    const float* __restrict__ w0, const float* __restrict__ w1,
    __hip_bfloat16* __restrict__ d0, __hip_bfloat16* __restrict__ d1,
    const float* __restrict__ ow1,
    __hip_bfloat16* __restrict__ of1hi, __hip_bfloat16* __restrict__ of1lo,
    const float* __restrict__ m0, const float* __restrict__ m1, const float* __restrict__ m2,
    float* __restrict__ mo) {
  int i = blockIdx.x * 256 + threadIdx.x;
  if (i < 1572864) {
    int l = i >= 786432;
    int i2 = i - (l ? 786432 : 0);
    const float* w = l ? w1 : w0;
    __hip_bfloat16* d = l ? d1 : d0;
    int fid = i2 >> 9, within = i2 & 511, lane = within >> 3, j = within & 7;
    int mb = fid / 48, kt = fid - mb * 48;
    int o = mb * 16 + (lane & 15);
    int r = kt * 32 + (lane >> 4) * 8 + j;
    int k = r >> 9, c = r & 511;
    d[i2] = __float2bfloat16(w[o * 1536 + c * 3 + k]);
  } else if (i < 1597440) {  // 1572864 + 24576 : owF1 hi+lo (one pass per elem)
    int i4 = i - 1572864;
    int fid = i4 >> 9, within = i4 & 511, lane = within >> 3, jj = within & 7;
    int o = lane & 15;
    int rr = fid * 32 + (lane >> 4) * 8 + jj;  // 0..1535
    int j = rr >> 9, c = rr & 511;
    float v = (o < 3) ? ow1[o * 1536 + c * 3 + j] : 0.f;
    __hip_bfloat16 hi = __float2bfloat16(v);
    of1hi[i4] = hi;
    of1lo[i4] = __float2bfloat16(v - __bfloat162float(hi));
  } else {
    int i2 = i - 1597440;
    if (i2 < 28672) {
      float v;
      if (i2 < 16384) v = m0[i2];
      else if (i2 < 24576) v = m1[i2 - 16384];
      else v = m2[i2 - 24576];
      mo[i2] = (v != 0.f) ? 1.f : 0.f;
    }
  }
}

// ---------- transpose feats (b,c,t) fp32 -> (b,t,c) bf16, 3 levels batched ----------
__global__ __launch_bounds__(256) void transpose_kernel(const float* __restrict__ x0,
                                                        const float* __restrict__ x1,
                                                        const float* __restrict__ x2,
                                                        __hip_bfloat16* __restrict__ xT) {
  __shared__ float fl[64][65];
  int f = blockIdx.x;
  int lv = (f < 2048) ? 0 : ((f < 3072) ? 1 : 2);
  int f2 = f - ((lv == 0) ? 0 : ((lv == 1) ? 2048 : 3072));
  int tsh = 11 - lv;
  const float* x = (lv == 0) ? x0 : ((lv == 1) ? x1 : x2);
  __hip_bfloat16* xo = xT + ((lv == 0) ? 0 : ((lv == 1) ? 8388608 : 12582912));
  int perb = (1 << (tsh - 6)) * 8;
  int b = f2 / perb;
  int rem = f2 - b * perb;
  int t0 = (rem >> 3) << 6;
  int c0 = (rem & 7) << 6;
  int tid = threadIdx.x;
  const float* xb = x + ((size_t)(b * 512 + c0) << tsh) + t0;
  // float4 loads: 64x64 tile = 1024 quads, 4 per thread
  int tq = tid & 15, cr = tid >> 4;
#pragma unroll
  for (int p = 0; p < 4; ++p) {
    int cl = cr + p * 16;
    f32x4 v = *(const f32x4*)(xb + ((size_t)cl << tsh) + (tq << 2));
#pragma unroll
    for (int j = 0; j < 4; ++j) fl[cl][(tq << 2) + j] = v[j];
  }
  __syncthreads();
  int tl2 = tid >> 2;
  int cb = (tid & 3) << 4;
  short* orow = (short*)xo + (((size_t)(b << tsh) + t0 + tl2) << 9) + c0 + cb;
#pragma unroll
  for (int h = 0; h < 2; ++h) {
    bf16x8 v;
#pragma unroll
    for (int j = 0; j < 8; ++j) v[j] = f2b(fl[cb + h * 8 + j][tl2]);
    *(bf16x8*)(orow + h * 8) = v;
  }
}

// ---------- layer-1 offset-conv partials, LDS-tiled, fp32 VALU ----------
// grid (448, 4): bx [0,256)=lv0, [256,384)=lv1, [384,448)=lv2; y = 128-c group.
// P level float offsets {0, 196608, 294912}; layout P[g*(24<<tsh) + ((b*3+k)<<tsh) + t].
__global__ __launch_bounds__(256) void offconv1_kernel(const float* __restrict__ x0p,
                                                       const float* __restrict__ x1p,
                                                       const float* __restrict__ x2p,
                                                       const float* __restrict__ ow,
                                                       float* __restrict__ P) {
  __shared__ float tile[128][66];  // [c][t]; col 64 = t-1 halo, col 65 = t+64 halo
  __shared__ float red[3][4][64];
  int tid = threadIdx.x, lane = tid & 63, w = tid >> 6;
  int bx = blockIdx.x;
  int lv = (bx < 256) ? 0 : ((bx < 384) ? 1 : 2);
  int lbx = bx - ((lv == 0) ? 0 : ((lv == 1) ? 256 : 384));
  int tsh = 11 - lv;
  int T = 1 << tsh;
  const float* x = (lv == 0) ? x0p : ((lv == 1) ? x1p : x2p);
  float* Pl = P + ((lv == 0) ? 0 : ((lv == 1) ? 196608 : 294912));
  int nchunk = T >> 6;
  int b = lbx >> (tsh - 6);
  int tb = (lbx & (nchunk - 1)) << 6;
  int c0g = blockIdx.y * 128;
  const float* xb = x + ((size_t)(b * 512 + c0g) << tsh);
  // stage main 128c x 64t via float4
  for (int idx = tid; idx < 2048; idx += 256) {
    int c = idx >> 4, tq = idx & 15;
    f32x4 v = *(const f32x4*)(xb + ((size_t)c << tsh) + tb + (tq << 2));
#pragma unroll
    for (int j = 0; j < 4; ++j) tile[c][(tq << 2) + j] = v[j];
  }
  // halo columns
  if (tid < 128) {
    int c = tid;
    tile[c][64] = (tb > 0) ? xb[((size_t)c << tsh) + tb - 1] : 0.f;
  } else {
    int c = tid - 128;
    tile[c][65] = (tb + 64 < T) ? xb[((size_t)c << tsh) + tb + 64] : 0.f;
  }
  __syncthreads();
  int im = (lane == 0) ? 64 : lane - 1;
  int ip = (lane == 63) ? 65 : lane + 1;
  float a0 = 0.f, a1 = 0.f, a2 = 0.f;
  for (int c = 0; c < 32; ++c) {
    int cc = w * 32 + c;
    float xm = tile[cc][im];
    float x0 = tile[cc][lane];
    float xp = tile[cc][ip];
    const float* wp = ow + (c0g + cc) * 3;
    a0 += wp[0] * xm + wp[1] * x0 + wp[2] * xp;
    a1 += wp[1536] * xm + wp[1537] * x0 + wp[1538] * xp;
    a2 += wp[3072] * xm + wp[3073] * x0 + wp[3074] * xp;
  }
  red[0][w][lane] = a0;
  red[1][w][lane] = a1;
  red[2][w][lane] = a2;
  __syncthreads();
  if (w < 3) {
    float s = red[w][0][lane] + red[w][1][lane] + red[w][2][lane] + red[w][3][lane];
    Pl[blockIdx.y * (24 << tsh) + ((b * 3 + w) << tsh) + tb + lane] = s;
  }
}

// ---------- layer-2 offset conv: skinny MFMA on x1T, ow in hi/lo bf16 ----------
// One wave per 16-n tile (1792 total); writes conv sum to offc2.
__global__ __launch_bounds__(256, 4) void offconv2_kernel(const __hip_bfloat16* __restrict__ xT,
                                                          const __hip_bfloat16* __restrict__ oHi,
                                                          const __hip_bfloat16* __restrict__ oLo,
                                                          float* __restrict__ offc) {
  int tid = threadIdx.x, lane = tid & 63, wid = tid >> 6;
  int nt = blockIdx.x * 4 + wid;
  int lv = (nt < 1024) ? 0 : ((nt < 1536) ? 1 : 2);
  int ntl = nt - ((lv == 0) ? 0 : ((lv == 1) ? 1024 : 1536));
  int tsh = 11 - lv;
  int T = 1 << tsh;
  const short* xp = (const short*)xT + ((lv == 0) ? 0 : ((lv == 1) ? 8388608 : 12582912));
  float* oc = offc + ((lv == 0) ? 0 : ((lv == 1) ? 49152 : 73728));
  int n = (ntl << 4) + (lane & 15);
  int b = n >> tsh;
  int t = n & (T - 1);
  const short* hip_ = (const short*)oHi + lane * 8;
  const short* lop_ = (const short*)oLo + lane * 8;
  int co = (lane >> 4) << 3;
  f32x4 acc = {};
  for (int kt = 0; kt < 48; ++kt) {
    int j = kt >> 4;
    int c0 = ((kt & 15) << 5) + co;
    int row = t + j - 1;
    bf16x8 bv = {};
    if ((unsigned)row < (unsigned)T)
      bv = *(const bf16x8*)(xp + (((size_t)(b << tsh) + row) << 9) + c0);
    bf16x8 ah = *(const bf16x8*)(hip_ + ((size_t)kt << 9));
    bf16x8 al = *(const bf16x8*)(lop_ + ((size_t)kt << 9));
    acc = __builtin_amdgcn_mfma_f32_16x16x32_bf16(ah, bv, acc, 0, 0, 0);
    acc = __builtin_amdgcn_mfma_f32_16x16x32_bf16(al, bv, acc, 0, 0, 0);
  }
  if ((lane >> 4) == 0) {
#pragma unroll
    for (int r = 0; r < 3; ++r) oc[((b * 3 + r) << tsh) + t] = acc[r];
  }
}

// ---------- fused deform-GEMM from transposed x ----------
// grid (224, 2): x = 128-t strip (level-batched), y = m-half (256 rows). 4 waves m-split.
// BK=64 per phase (24 phases): issue gathers for S(p+1) at phase top, 64 MFMA on S(p),
// lerp+write S(p+1) at phase bottom (full-phase latency cover), one barrier per phase.
template <bool LAYER2, bool OUT_BF16>
__global__ __launch_bounds__(256, 2) void dgemm_kernel(
    const __hip_bfloat16* __restrict__ xT, const __hip_bfloat16* __restrict__ Wf,
    const float* __restrict__ off0, const float* __restrict__ off1,
    const float* __restrict__ off2, const float* __restrict__ P1,
    const float* __restrict__ offc2, const float* __restrict__ ob0v,
    const float* __restrict__ ob1v, const float* __restrict__ bias,
    const float* __restrict__ mk0, const float* __restrict__ mk1, const float* __restrict__ mk2,
    void* __restrict__ o0, void* __restrict__ o1, void* __restrict__ o2) {
  __shared__ short sS[2][8192];  // [buf][128t x 64k] as 8 chunks x (2 kh x 512)
  __shared__ int s_q[3][128];
  __shared__ float s_w0[3][128];
  __shared__ float s_w1[3][128];
  int tid = threadIdx.x, lane = tid & 63, wid = tid >> 6;
  int bx = blockIdx.x;
  int lv = (bx < 128) ? 0 : ((bx < 192) ? 1 : 2);
  int lbx = bx - ((lv == 0) ? 0 : ((lv == 1) ? 128 : 192));
  int tsh = 11 - lv;
  int T = 1 << tsh;
  const short* xp = (const short*)xT + ((lv == 0) ? 0 : ((lv == 1) ? 8388608 : 12582912));
  const float* offin = (lv == 0) ? off0 : ((lv == 1) ? off1 : off2);
  const float* P1l = P1 + ((lv == 0) ? 0 : ((lv == 1) ? 196608 : 294912));
  const float* oc2 = offc2 + ((lv == 0) ? 0 : ((lv == 1) ? 49152 : 73728));
  const float* mask = (lv == 0) ? mk0 : ((lv == 1) ? mk1 : mk2);
  void* outp = (lv == 0) ? o0 : ((lv == 1) ? o1 : o2);
  int nchunk = T >> 7;
  int b = lbx >> (tsh - 7);
  int tb = (lbx & (nchunk - 1)) << 7;
  int mhalf = blockIdx.y;

  // per-(tap,t) sample params: clamped rows + zeroable weights
  for (int idx = tid; idx < 384; idx += 256) {
    int k = idx >> 7, tl = idx & 127, t = tb + tl;
    int oi = ((b * 3 + k) << tsh) + t;
    int PT = 24 << tsh;
    float o = offin[oi] + ob0v[k];
    o += P1l[oi] + P1l[PT + oi] + P1l[2 * PT + oi] + P1l[3 * PT + oi];
    if (LAYER2) o += ob1v[k] + oc2[oi];
    float pos = (float)(t + k - 1) + o;
    float pf = floorf(pos);
    float fr = pos - pf;
    int q0 = (int)pf;
    int q1 = q0 + 1;
    bool ok0 = (unsigned)q0 < (unsigned)T;
    bool ok1 = (unsigned)q1 < (unsigned)T;
    int q0c = min(max(q0, 0), T - 1);
    int q1c = min(max(q1, 0), T - 1);
    s_q[k][tl] = (q0c & 0xffff) | (q1c << 16);
    s_w0[k][tl] = ok0 ? (1.f - fr) : 0.f;
    s_w1[k][tl] = ok1 ? fr : 0.f;
  }
  __syncthreads();

  // hoist params: (k3, half h) -> rows + weights; wave stages chunks wid (h=0), wid+4 (h=1)
  int q0r[3][2], q1r[3][2];
  float w0r[3][2], w1r[3][2];
#pragma unroll
  for (int k3 = 0; k3 < 3; ++k3)
#pragma unroll
    for (int h = 0; h < 2; ++h) {
      int tl = h * 64 + wid * 16 + (lane & 15);
      int qp = s_q[k3][tl];
      q0r[k3][h] = qp & 0xffff;
      q1r[k3][h] = (qp >> 16) & 0xffff;
      w0r[k3][h] = s_w0[k3][tl];
      w1r[k3][h] = s_w1[k3][tl];
    }
  int aq0[2] = {q0r[0][0], q0r[0][1]}, aq1[2] = {q1r[0][0], q1r[0][1]};
  float aw0[2] = {w0r[0][0], w0r[0][1]}, aw1[2] = {w1r[0][0], w1r[0][1]};

  f32x4 acc[4][8] = {};
  const short* wfp = (const short*)Wf + (size_t)(mhalf * 16 + wid * 4) * 48 * 512 + lane * 8;
  unsigned co = (unsigned)((lane >> 4) << 3);
  const short* xrow = xp + (((size_t)(b << tsh)) << 9);
  short* smy = &sS[0][0] + ((wid << 10) + lane * 8);  // chunk wid; h adds <<12, kh adds <<9
  const short* smrd = &sS[0][0] + lane * 8;

  // ---- prologue: stage S(0) (kts 0,1) into buf0 ----
  {
    bf16x8 g0[2][2], g1[2][2];
#pragma unroll
    for (int h = 0; h < 2; ++h) {
      unsigned r0 = ((unsigned)aq0[h]) << 9, r1 = ((unsigned)aq1[h]) << 9;
      g0[h][0] = *(const bf16x8*)(xrow + r0 + co);
      g0[h][1] = *(const bf16x8*)(xrow + r0 + 32 + co);
      g1[h][0] = *(const bf16x8*)(xrow + r1 + co);
      g1[h][1] = *(const bf16x8*)(xrow + r1 + 32 + co);
    }
#pragma unroll
    for (int h = 0; h < 2; ++h)
#pragma unroll
      for (int kh = 0; kh < 2; ++kh) {
        bf16x8 ov;
#pragma unroll
        for (int j = 0; j < 8; ++j)
          ov[j] = f2b(b2f(g0[h][kh][j]) * aw0[h] + b2f(g1[h][kh][j]) * aw1[h]);
        *(bf16x8*)(smy + (h << 12) + (kh << 9)) = ov;
      }
    asm volatile("s_waitcnt lgkmcnt(0)" ::: "memory");
    __builtin_amdgcn_s_barrier();
    asm volatile("" ::: "memory");
  }

#pragma unroll 2
  for (int p = 0; p < 24; ++p) {
    int cur = p & 1;
    // tap switch for staging pair sp = p+1 (covers kts 2sp, 2sp+1; tap = sp>>3)
    if (p == 7) {
#pragma unroll
      for (int h = 0; h < 2; ++h) {
        aq0[h] = q0r[1][h]; aq1[h] = q1r[1][h];
        aw0[h] = w0r[1][h]; aw1[h] = w1r[1][h];
      }
    } else if (p == 15) {
#pragma unroll
      for (int h = 0; h < 2; ++h) {
        aq0[h] = q0r[2][h]; aq1[h] = q1r[2][h];
        aw0[h] = w0r[2][h]; aw1[h] = w1r[2][h];
      }
    }
    // issue gathers for S(p+1) early (consumed at phase bottom)
    bf16x8 g0[2][2], g1[2][2];
    if (p < 23) {
      unsigned cb = ((unsigned)((2 * (p + 1)) & 15)) << 5;
#pragma unroll
      for (int h = 0; h < 2; ++h) {
        unsigned r0 = ((unsigned)aq0[h]) << 9, r1 = ((unsigned)aq1[h]) << 9;
        g0[h][0] = *(const bf16x8*)(xrow + r0 + cb + co);
        g0[h][1] = *(const bf16x8*)(xrow + r0 + cb + 32 + co);
        g1[h][0] = *(const bf16x8*)(xrow + r1 + cb + co);
        g1[h][1] = *(const bf16x8*)(xrow + r1 + cb + 32 + co);
      }
    }
    // A frags for this phase (kts 2p, 2p+1)
    bf16x8 A[4][2];
#pragma unroll
    for (int i = 0; i < 4; ++i)
#pragma unroll
      for (int kh = 0; kh < 2; ++kh)
        A[i][kh] = *(const bf16x8*)(wfp + ((size_t)(i * 48 + 2 * p + kh) << 9));
    // 64 MFMA on S(p) from buf[cur], split by kh
#pragma unroll
    for (int kh = 0; kh < 2; ++kh) {
      bf16x8 bv[8];
#pragma unroll
      for (int jj = 0; jj < 8; ++jj)
        bv[jj] = *(const bf16x8*)(smrd + (cur << 13) + (jj << 10) + (kh << 9));
      __builtin_amdgcn_s_setprio(1);
#pragma unroll
      for (int i = 0; i < 4; ++i)
#pragma unroll
        for (int jj = 0; jj < 8; ++jj)
          acc[i][jj] =
              __builtin_amdgcn_mfma_f32_16x16x32_bf16(A[i][kh], bv[jj], acc[i][jj], 0, 0, 0);
      __builtin_amdgcn_s_setprio(0);
    }
    // lerp + stage S(p+1) into buf[cur^1]
    if (p < 23) {
      short* smw = smy + ((cur ^ 1) << 13);
#pragma unroll
      for (int h = 0; h < 2; ++h)
#pragma unroll
        for (int kh = 0; kh < 2; ++kh) {
          bf16x8 ov;
#pragma unroll
          for (int j = 0; j < 8; ++j)
            ov[j] = f2b(b2f(g0[h][kh][j]) * aw0[h] + b2f(g1[h][kh][j]) * aw1[h]);
          *(bf16x8*)(smw + (h << 12) + (kh << 9)) = ov;
        }
      asm volatile("s_waitcnt lgkmcnt(0)" ::: "memory");
      __builtin_amdgcn_s_barrier();
      asm volatile("" ::: "memory");
    }
  }

  // epilogue: D row = (lane>>4)*4 + reg (m), col = lane&15 (t); 8 t-tiles
  int lrow = lane & 15, lq = lane >> 4;
  int mbase = mhalf * 256 + wid * 64;
  float bvals[4][4];
#pragma unroll
  for (int i = 0; i < 4; ++i)
#pragma unroll
    for (int r = 0; r < 4; ++r) bvals[i][r] = bias[mbase + i * 16 + lq * 4 + r];
#pragma unroll
  for (int j = 0; j < 8; ++j) {
    int col = j * 16 + lrow;
    int t = tb + col;
    float mk = mask[(b << tsh) + t];
    if (OUT_BF16) {
      short* orow = (short*)outp + (((size_t)(b << tsh) + t) << 9);
#pragma unroll
      for (int i = 0; i < 4; ++i) {
        bf16x4 pv;
#pragma unroll
        for (int r = 0; r < 4; ++r)
          pv[r] = f2b(fmaxf(acc[i][j][r] + bvals[i][r], 0.f) * mk);
        *(bf16x4*)(orow + mbase + i * 16 + lq * 4) = pv;
      }
    } else {
#pragma unroll
      for (int i = 0; i < 4; ++i) {
        int m = mbase + i * 16 + lq * 4;
#pragma unroll
        for (int r = 0; r < 4; ++r) {
          float v = fmaxf(acc[i][j][r] + bvals[i][r], 0.f) * mk;
          ((float*)outp)[(((size_t)(b * 512 + m + r)) << tsh) + t] = v;
        }
      }
    }
  }
}

// ---------- launch ----------
extern "C" void kernel_launch(void* const* d_in, const int* in_sizes, int n_in, void* d_out,
                              int out_size, void* d_ws, size_t ws_size, hipStream_t stream) {
  const float* feats[3] = {(const float*)d_in[0], (const float*)d_in[3], (const float*)d_in[6]};
  const float* maskp[3] = {(const float*)d_in[1], (const float*)d_in[4], (const float*)d_in[7]};
  const float* offs[3] = {(const float*)d_in[2], (const float*)d_in[5], (const float*)d_in[8]};
  const float* w[2] = {(const float*)d_in[9], (const float*)d_in[13]};
  const float* bias[2] = {(const float*)d_in[10], (const float*)d_in[14]};
  const float* ow[2] = {(const float*)d_in[11], (const float*)d_in[15]};
  const float* ob[2] = {(const float*)d_in[12], (const float*)d_in[16]};

  const size_t YOFF[3] = {0, 8388608, 12582912};
  const size_t MOFF = 14680064;

  uint8_t* ws = (uint8_t*)d_ws;
  __hip_bfloat16* Wf0 = (__hip_bfloat16*)ws;                 // 1,572,864 B
  __hip_bfloat16* Wf1 = (__hip_bfloat16*)(ws + 1572864);     // 1,572,864 B
  __hip_bfloat16* owF1hi = (__hip_bfloat16*)(ws + 3145728);  // 49,152 B
  __hip_bfloat16* owF1lo = (__hip_bfloat16*)(ws + 3194880);  // 49,152 B
  float* P1 = (float*)(ws + 3244032);                        // 1,376,256 B
  float* offc2 = (float*)(ws + 4620288);                     // 344,064 B
  __hip_bfloat16* fT = (__hip_bfloat16*)(ws + 8388608);      // 29,360,128 B
  __hip_bfloat16* x1T = (__hip_bfloat16*)(ws + 37748736);    // 29,360,128 B (end 67,108,864)

  float* outf = (float*)d_out;

  setup_kernel<<<6448, 256, 0, stream>>>(w[0], w[1], Wf0, Wf1, ow[1], owF1hi, owF1lo,
                                         maskp[0], maskp[1], maskp[2], outf + MOFF);
  transpose_kernel<<<3584, 256, 0, stream>>>(feats[0], feats[1], feats[2], fT);
  offconv1_kernel<<<dim3(448, 4), 256, 0, stream>>>(feats[0], feats[1], feats[2], ow[0], P1);

  // layer 1
  dgemm_kernel<false, true><<<dim3(224, 2), 256, 0, stream>>>(
      fT, Wf0, offs[0], offs[1], offs[2], P1, offc2, ob[0], ob[1], bias[0],
      maskp[0], maskp[1], maskp[2], (void*)x1T, (void*)(x1T + YOFF[1]), (void*)(x1T + YOFF[2]));

  // layer 2
  offconv2_kernel<<<448, 256, 0, stream>>>(x1T, owF1hi, owF1lo, offc2);
  dgemm_kernel<true, false><<<dim3(224, 2), 256, 0, stream>>>(
      x1T, Wf1, offs[0], offs[1], offs[2], P1, offc2, ob[0], ob[1], bias[1],
      maskp[0], maskp[1], maskp[2], (void*)(outf + YOFF[0]), (void*)(outf + YOFF[1]),
      (void*)(outf + YOFF[2]));
}

// Round 4
// 341.174 us; speedup vs baseline: 1.4106x; 1.4106x over previous
//
#include <hip/hip_runtime.h>
#include <hip/hip_bf16.h>
#include <stdint.h>

typedef __attribute__((ext_vector_type(8))) short bf16x8;
typedef __attribute__((ext_vector_type(4))) short bf16x4;
typedef __attribute__((ext_vector_type(4))) float f32x4;

__device__ __forceinline__ float b2f(short s) {
  union { unsigned u; float f; } cv;
  cv.u = ((unsigned)(unsigned short)s) << 16;
  return cv.f;
}
__device__ __forceinline__ short f2b(float f) {
  __hip_bfloat16 h = __float2bfloat16(f);
  return *reinterpret_cast<short*>(&h);
}
__device__ __forceinline__ void ldsdma16(const short* g, short* l) {
  __builtin_amdgcn_global_load_lds((const __attribute__((address_space(1))) unsigned int*)g,
                                   (__attribute__((address_space(3))) unsigned int*)l, 16, 0, 0);
}

// Layouts:
//  xT[b][t][c] bf16 (c contiguous, 512/row), per-level elem offsets {0, 8388608, 12582912}.
//  W frags (k-major r = k*512+c): fid = mb*48+kt, lane l: o = mb*16+(l&15), r = kt*32+(l>>4)*8+j.
//  owF1 frags (j-major rr = j*512+c): fid = kt (0..47), lane l: k = l&15 (rows>=3 zero),
//    rr = kt*32+(l>>4)*8+j; stored twice: hi = bf16(v), lo = bf16(v - hi).

// ---------- setup: pack W0/W1 frags, owF1 hi/lo frags, mask outputs ----------
__global__ __launch_bounds__(256) void setup_kernel(
    const float* __restrict__ w0, const float* __restrict__ w1,
    __hip_bfloat16* __restrict__ d0, __hip_bfloat16* __restrict__ d1,
    const float* __restrict__ ow1,
    __hip_bfloat16* __restrict__ of1hi, __hip_bfloat16* __restrict__ of1lo,
    const float* __restrict__ m0, const float* __restrict__ m1, const float* __restrict__ m2,
    float* __restrict__ mo) {
  int i = blockIdx.x * 256 + threadIdx.x;
  if (i < 1572864) {
    int l = i >= 786432;
    int i2 = i - (l ? 786432 : 0);
    const float* w = l ? w1 : w0;
    __hip_bfloat16* d = l ? d1 : d0;
    int fid = i2 >> 9, within = i2 & 511, lane = within >> 3, j = within & 7;
    int mb = fid / 48, kt = fid - mb * 48;
    int o = mb * 16 + (lane & 15);
    int r = kt * 32 + (lane >> 4) * 8 + j;
    int k = r >> 9, c = r & 511;
    d[i2] = __float2bfloat16(w[o * 1536 + c * 3 + k]);
  } else if (i < 1597440) {  // 1572864 + 24576 : owF1 hi+lo (one pass per elem)
    int i4 = i - 1572864;
    int fid = i4 >> 9, within = i4 & 511, lane = within >> 3, jj = within & 7;
    int o = lane & 15;
    int rr = fid * 32 + (lane >> 4) * 8 + jj;  // 0..1535
    int j = rr >> 9, c = rr & 511;
    float v = (o < 3) ? ow1[o * 1536 + c * 3 + j] : 0.f;
    __hip_bfloat16 hi = __float2bfloat16(v);
    of1hi[i4] = hi;
    of1lo[i4] = __float2bfloat16(v - __bfloat162float(hi));
  } else {
    int i2 = i - 1597440;
    if (i2 < 28672) {
      float v;
      if (i2 < 16384) v = m0[i2];
      else if (i2 < 24576) v = m1[i2 - 16384];
      else v = m2[i2 - 24576];
      mo[i2] = (v != 0.f) ? 1.f : 0.f;
    }
  }
}

// ---------- transpose feats (b,c,t) fp32 -> (b,t,c) bf16, 3 levels batched ----------
__global__ __launch_bounds__(256) void transpose_kernel(const float* __restrict__ x0,
                                                        const float* __restrict__ x1,
                                                        const float* __restrict__ x2,
                                                        __hip_bfloat16* __restrict__ xT) {
  __shared__ float fl[64][65];
  int f = blockIdx.x;
  int lv = (f < 2048) ? 0 : ((f < 3072) ? 1 : 2);
  int f2 = f - ((lv == 0) ? 0 : ((lv == 1) ? 2048 : 3072));
  int tsh = 11 - lv;
  const float* x = (lv == 0) ? x0 : ((lv == 1) ? x1 : x2);
  __hip_bfloat16* xo = xT + ((lv == 0) ? 0 : ((lv == 1) ? 8388608 : 12582912));
  int perb = (1 << (tsh - 6)) * 8;
  int b = f2 / perb;
  int rem = f2 - b * perb;
  int t0 = (rem >> 3) << 6;
  int c0 = (rem & 7) << 6;
  int tid = threadIdx.x;
  const float* xb = x + ((size_t)(b * 512 + c0) << tsh) + t0;
  // float4 loads: 64x64 tile = 1024 quads, 4 per thread
  int tq = tid & 15, cr = tid >> 4;
#pragma unroll
  for (int p = 0; p < 4; ++p) {
    int cl = cr + p * 16;
    f32x4 v = *(const f32x4*)(xb + ((size_t)cl << tsh) + (tq << 2));
#pragma unroll
    for (int j = 0; j < 4; ++j) fl[cl][(tq << 2) + j] = v[j];
  }
  __syncthreads();
  int tl2 = tid >> 2;
  int cb = (tid & 3) << 4;
  short* orow = (short*)xo + (((size_t)(b << tsh) + t0 + tl2) << 9) + c0 + cb;
#pragma unroll
  for (int h = 0; h < 2; ++h) {
    bf16x8 v;
#pragma unroll
    for (int j = 0; j < 8; ++j) v[j] = f2b(fl[cb + h * 8 + j][tl2]);
    *(bf16x8*)(orow + h * 8) = v;
  }
}

// ---------- layer-1 offset-conv partials, LDS-tiled, fp32 VALU ----------
// grid (448, 4): bx [0,256)=lv0, [256,384)=lv1, [384,448)=lv2; y = 128-c group.
// P level float offsets {0, 196608, 294912}; layout P[g*(24<<tsh) + ((b*3+k)<<tsh) + t].
__global__ __launch_bounds__(256) void offconv1_kernel(const float* __restrict__ x0p,
                                                       const float* __restrict__ x1p,
                                                       const float* __restrict__ x2p,
                                                       const float* __restrict__ ow,
                                                       float* __restrict__ P) {
  __shared__ float tile[128][66];  // [c][t]; col 64 = t-1 halo, col 65 = t+64 halo
  __shared__ float red[3][4][64];
  int tid = threadIdx.x, lane = tid & 63, w = tid >> 6;
  int bx = blockIdx.x;
  int lv = (bx < 256) ? 0 : ((bx < 384) ? 1 : 2);
  int lbx = bx - ((lv == 0) ? 0 : ((lv == 1) ? 256 : 384));
  int tsh = 11 - lv;
  int T = 1 << tsh;
  const float* x = (lv == 0) ? x0p : ((lv == 1) ? x1p : x2p);
  float* Pl = P + ((lv == 0) ? 0 : ((lv == 1) ? 196608 : 294912));
  int nchunk = T >> 6;
  int b = lbx >> (tsh - 6);
  int tb = (lbx & (nchunk - 1)) << 6;
  int c0g = blockIdx.y * 128;
  const float* xb = x + ((size_t)(b * 512 + c0g) << tsh);
  // stage main 128c x 64t via float4
  for (int idx = tid; idx < 2048; idx += 256) {
    int c = idx >> 4, tq = idx & 15;
    f32x4 v = *(const f32x4*)(xb + ((size_t)c << tsh) + tb + (tq << 2));
#pragma unroll
    for (int j = 0; j < 4; ++j) tile[c][(tq << 2) + j] = v[j];
  }
  // halo columns
  if (tid < 128) {
    int c = tid;
    tile[c][64] = (tb > 0) ? xb[((size_t)c << tsh) + tb - 1] : 0.f;
  } else {
    int c = tid - 128;
    tile[c][65] = (tb + 64 < T) ? xb[((size_t)c << tsh) + tb + 64] : 0.f;
  }
  __syncthreads();
  int im = (lane == 0) ? 64 : lane - 1;
  int ip = (lane == 63) ? 65 : lane + 1;
  float a0 = 0.f, a1 = 0.f, a2 = 0.f;
  for (int c = 0; c < 32; ++c) {
    int cc = w * 32 + c;
    float xm = tile[cc][im];
    float x0 = tile[cc][lane];
    float xp = tile[cc][ip];
    const float* wp = ow + (c0g + cc) * 3;
    a0 += wp[0] * xm + wp[1] * x0 + wp[2] * xp;
    a1 += wp[1536] * xm + wp[1537] * x0 + wp[1538] * xp;
    a2 += wp[3072] * xm + wp[3073] * x0 + wp[3074] * xp;
  }
  red[0][w][lane] = a0;
  red[1][w][lane] = a1;
  red[2][w][lane] = a2;
  __syncthreads();
  if (w < 3) {
    float s = red[w][0][lane] + red[w][1][lane] + red[w][2][lane] + red[w][3][lane];
    Pl[blockIdx.y * (24 << tsh) + ((b * 3 + w) << tsh) + tb + lane] = s;
  }
}

// ---------- layer-2 offset conv: skinny MFMA on x1T, ow in hi/lo bf16 ----------
// One wave per 16-n tile (1792 total); writes conv sum to offc2.
__global__ __launch_bounds__(256, 4) void offconv2_kernel(const __hip_bfloat16* __restrict__ xT,
                                                          const __hip_bfloat16* __restrict__ oHi,
                                                          const __hip_bfloat16* __restrict__ oLo,
                                                          float* __restrict__ offc) {
  int tid = threadIdx.x, lane = tid & 63, wid = tid >> 6;
  int nt = blockIdx.x * 4 + wid;
  int lv = (nt < 1024) ? 0 : ((nt < 1536) ? 1 : 2);
  int ntl = nt - ((lv == 0) ? 0 : ((lv == 1) ? 1024 : 1536));
  int tsh = 11 - lv;
  int T = 1 << tsh;
  const short* xp = (const short*)xT + ((lv == 0) ? 0 : ((lv == 1) ? 8388608 : 12582912));
  float* oc = offc + ((lv == 0) ? 0 : ((lv == 1) ? 49152 : 73728));
  int n = (ntl << 4) + (lane & 15);
  int b = n >> tsh;
  int t = n & (T - 1);
  const short* hip_ = (const short*)oHi + lane * 8;
  const short* lop_ = (const short*)oLo + lane * 8;
  int co = (lane >> 4) << 3;
  f32x4 acc = {};
  for (int kt = 0; kt < 48; ++kt) {
    int j = kt >> 4;
    int c0 = ((kt & 15) << 5) + co;
    int row = t + j - 1;
    bf16x8 bv = {};
    if ((unsigned)row < (unsigned)T)
      bv = *(const bf16x8*)(xp + (((size_t)(b << tsh) + row) << 9) + c0);
    bf16x8 ah = *(const bf16x8*)(hip_ + ((size_t)kt << 9));
    bf16x8 al = *(const bf16x8*)(lop_ + ((size_t)kt << 9));
    acc = __builtin_amdgcn_mfma_f32_16x16x32_bf16(ah, bv, acc, 0, 0, 0);
    acc = __builtin_amdgcn_mfma_f32_16x16x32_bf16(al, bv, acc, 0, 0, 0);
  }
  if ((lane >> 4) == 0) {
#pragma unroll
    for (int r = 0; r < 3; ++r) oc[((b * 3 + r) << tsh) + t] = acc[r];
  }
}

// ---------- fused deform-GEMM from transposed x ----------
// grid (224, 2): x = 128-t strip (level-batched), y = m-half (256 rows). 4 waves m-split.
// BK=32, 48 phases. W frags stream global->LDS via async global_load_lds DMA (0 VGPR,
// dbuf in LDS); gathers are 2-phase-deep register prefetch (2 alternating 16-reg sets);
// counted vmcnt(4) spans the barrier (only last staging phase drains to 0).
template <bool LAYER2, bool OUT_BF16>
__global__ __launch_bounds__(256, 2) void dgemm_kernel(
    const __hip_bfloat16* __restrict__ xT, const __hip_bfloat16* __restrict__ Wf,
    const float* __restrict__ off0, const float* __restrict__ off1,
    const float* __restrict__ off2, const float* __restrict__ P1,
    const float* __restrict__ offc2, const float* __restrict__ ob0v,
    const float* __restrict__ ob1v, const float* __restrict__ bias,
    const float* __restrict__ mk0, const float* __restrict__ mk1, const float* __restrict__ mk2,
    void* __restrict__ o0, void* __restrict__ o1, void* __restrict__ o2) {
  __shared__ short sS[2][4096];        // S dbuf: [buf][8 chunks x 512]
  __shared__ short wlds[2][4][2048];   // W dbuf: [parity][wave][4 frags x 512]
  __shared__ int s_q[3][128];
  __shared__ float s_w0[3][128];
  __shared__ float s_w1[3][128];
  int tid = threadIdx.x, lane = tid & 63, wid = tid >> 6;
  int bx = blockIdx.x;
  int lv = (bx < 128) ? 0 : ((bx < 192) ? 1 : 2);
  int lbx = bx - ((lv == 0) ? 0 : ((lv == 1) ? 128 : 192));
  int tsh = 11 - lv;
  int T = 1 << tsh;
  const short* xp = (const short*)xT + ((lv == 0) ? 0 : ((lv == 1) ? 8388608 : 12582912));
  const float* offin = (lv == 0) ? off0 : ((lv == 1) ? off1 : off2);
  const float* P1l = P1 + ((lv == 0) ? 0 : ((lv == 1) ? 196608 : 294912));
  const float* oc2 = offc2 + ((lv == 0) ? 0 : ((lv == 1) ? 49152 : 73728));
  const float* mask = (lv == 0) ? mk0 : ((lv == 1) ? mk1 : mk2);
  void* outp = (lv == 0) ? o0 : ((lv == 1) ? o1 : o2);
  int nchunk = T >> 7;
  int b = lbx >> (tsh - 7);
  int tb = (lbx & (nchunk - 1)) << 7;
  int mhalf = blockIdx.y;

  // per-(tap,t) sample params: clamped rows + zeroable weights
  for (int idx = tid; idx < 384; idx += 256) {
    int k = idx >> 7, tl = idx & 127, t = tb + tl;
    int oi = ((b * 3 + k) << tsh) + t;
    int PT = 24 << tsh;
    float o = offin[oi] + ob0v[k];
    o += P1l[oi] + P1l[PT + oi] + P1l[2 * PT + oi] + P1l[3 * PT + oi];
    if (LAYER2) o += ob1v[k] + oc2[oi];
    float pos = (float)(t + k - 1) + o;
    float pf = floorf(pos);
    float fr = pos - pf;
    int q0 = (int)pf;
    int q1 = q0 + 1;
    bool ok0 = (unsigned)q0 < (unsigned)T;
    bool ok1 = (unsigned)q1 < (unsigned)T;
    int q0c = min(max(q0, 0), T - 1);
    int q1c = min(max(q1, 0), T - 1);
    s_q[k][tl] = (q0c & 0xffff) | (q1c << 16);
    s_w0[k][tl] = ok0 ? (1.f - fr) : 0.f;
    s_w1[k][tl] = ok1 ? fr : 0.f;
  }
  __syncthreads();

  int tlh0 = wid * 16 + (lane & 15);
  int tlh1 = 64 + wid * 16 + (lane & 15);

  // active gather-issue params (tap of tile being ISSUED)
  int aq0[2], aq1[2];
  float aw0[2], aw1[2];
#define LOADTAP(K)                                   \
  {                                                  \
    int qp0 = s_q[K][tlh0], qp1 = s_q[K][tlh1];      \
    aq0[0] = qp0 & 0xffff; aq1[0] = (qp0 >> 16);     \
    aq0[1] = qp1 & 0xffff; aq1[1] = (qp1 >> 16);     \
    aw0[0] = s_w0[K][tlh0]; aw1[0] = s_w1[K][tlh0];  \
    aw0[1] = s_w0[K][tlh1]; aw1[1] = s_w1[K][tlh1];  \
  }
  LOADTAP(0)

  f32x4 acc[4][8] = {};
  const short* wfp = (const short*)Wf + (size_t)(mhalf * 16 + wid * 4) * 48 * 512 + lane * 8;
  unsigned co = (unsigned)((lane >> 4) << 3);
  const short* xrow = xp + (((size_t)(b << tsh)) << 9);
  short* smy = &sS[0][0] + (wid << 9) + lane * 8;  // +h*2048, +buf*4096
  const short* smrd = &sS[0][0] + lane * 8;        // +buf*4096 + jj*512
  short* wl0 = &wlds[0][wid][0];                   // DMA dest (wave-uniform)
  short* wl1 = &wlds[1][wid][0];
  const short* wlr = &wlds[0][wid][0] + lane * 8;  // read base; parity adds 8192

  // two gather register sets, each carrying its lerp weights
  bf16x8 gA0[2], gA1[2], gB0[2], gB1[2];
  float wA0[2], wA1[2], wB0[2], wB1[2];

  // ---- prologue: G(0)->setA, W(0) DMA->par0, G(1)->setB, lerp setA -> S(0) buf0 ----
  {
#pragma unroll
    for (int h = 0; h < 2; ++h) {
      gA0[h] = *(const bf16x8*)(xrow + (((unsigned)aq0[h]) << 9) + co);
      gA1[h] = *(const bf16x8*)(xrow + (((unsigned)aq1[h]) << 9) + co);
      wA0[h] = aw0[h]; wA1[h] = aw1[h];
    }
#pragma unroll
    for (int i = 0; i < 4; ++i) ldsdma16(wfp + ((size_t)(i * 48) << 9), wl0 + (i << 9));
#pragma unroll
    for (int h = 0; h < 2; ++h) {
      gB0[h] = *(const bf16x8*)(xrow + (((unsigned)aq0[h]) << 9) + 32 + co);
      gB1[h] = *(const bf16x8*)(xrow + (((unsigned)aq1[h]) << 9) + 32 + co);
      wB0[h] = aw0[h]; wB1[h] = aw1[h];
    }
#pragma unroll
    for (int h = 0; h < 2; ++h) {
      bf16x8 ov;
#pragma unroll
      for (int j = 0; j < 8; ++j)
        ov[j] = f2b(b2f(gA0[h][j]) * wA0[h] + b2f(gA1[h][j]) * wA1[h]);
      *(bf16x8*)(smy + (h << 11)) = ov;
    }
    asm volatile("s_waitcnt vmcnt(4) lgkmcnt(0)" ::: "memory");
    __builtin_amdgcn_s_barrier();
    asm volatile("" ::: "memory");
  }

  // phase p: MFMA on S(p)/W(p) [parity p&1]; DMA W(p+1); issue G(p+2) into set (p even: A, odd: B);
  // lerp other set (= G(p+1)) -> S(p+1); vmcnt(4) + barrier (vmcnt(0) at p==46).
#define DGP(P, CUR, GI0, GI1, WI0, WI1, GL0, GL1, WL0, WL1)                         \
  {                                                                                 \
    const int p_ = (P);                                                             \
    if (p_ == 14) LOADTAP(1)                                                        \
    else if (p_ == 30) LOADTAP(2)                                                   \
    if (p_ < 47) {                                                                  \
      short* wdst = (CUR) ? wl0 : wl1;                                              \
      _Pragma("unroll")                                                             \
      for (int i = 0; i < 4; ++i)                                                   \
        ldsdma16(wfp + ((size_t)(i * 48 + p_ + 1) << 9), wdst + (i << 9));          \
    }                                                                               \
    if (p_ < 46) {                                                                  \
      unsigned cb_ = ((unsigned)((p_ + 2) & 15)) << 5;                              \
      _Pragma("unroll")                                                             \
      for (int h = 0; h < 2; ++h) {                                                 \
        GI0[h] = *(const bf16x8*)(xrow + (((unsigned)aq0[h]) << 9) + cb_ + co);     \
        GI1[h] = *(const bf16x8*)(xrow + (((unsigned)aq1[h]) << 9) + cb_ + co);     \
        WI0[h] = aw0[h]; WI1[h] = aw1[h];                                           \
      }                                                                             \
    }                                                                               \
    bf16x8 A_[4];                                                                   \
    const short* wrd = wlr + ((CUR) ? 8192 : 0);                                    \
    _Pragma("unroll")                                                               \
    for (int i = 0; i < 4; ++i) A_[i] = *(const bf16x8*)(wrd + (i << 9));           \
    bf16x8 bv_[8];                                                                  \
    const short* sb_ = smrd + ((CUR) << 12);                                        \
    _Pragma("unroll")                                                               \
    for (int jj = 0; jj < 8; ++jj) bv_[jj] = *(const bf16x8*)(sb_ + (jj << 9));     \
    __builtin_amdgcn_s_setprio(1);                                                  \
    _Pragma("unroll")                                                               \
    for (int i = 0; i < 4; ++i)                                                     \
      _Pragma("unroll")                                                             \
      for (int jj = 0; jj < 8; ++jj)                                                \
        acc[i][jj] = __builtin_amdgcn_mfma_f32_16x16x32_bf16(A_[i], bv_[jj],        \
                                                             acc[i][jj], 0, 0, 0); \
    __builtin_amdgcn_s_setprio(0);                                                  \
    if (p_ < 47) {                                                                  \
      short* smw = smy + (((CUR) ^ 1) << 12);                                       \
      _Pragma("unroll")                                                             \
      for (int h = 0; h < 2; ++h) {                                                 \
        bf16x8 ov;                                                                  \
        _Pragma("unroll")                                                           \
        for (int j = 0; j < 8; ++j)                                                 \
          ov[j] = f2b(b2f(GL0[h][j]) * WL0[h] + b2f(GL1[h][j]) * WL1[h]);           \
        *(bf16x8*)(smw + (h << 11)) = ov;                                           \
      }                                                                             \
      if (p_ < 46)                                                                  \
        asm volatile("s_waitcnt vmcnt(4) lgkmcnt(0)" ::: "memory");                 \
      else                                                                          \
        asm volatile("s_waitcnt vmcnt(0) lgkmcnt(0)" ::: "memory");                 \
      __builtin_amdgcn_s_barrier();                                                 \
      asm volatile("" ::: "memory");                                                \
    }                                                                               \
  }

  for (int pp = 0; pp < 24; ++pp) {
    DGP(2 * pp, 0, gA0, gA1, wA0, wA1, gB0, gB1, wB0, wB1)
    DGP(2 * pp + 1, 1, gB0, gB1, wB0, wB1, gA0, gA1, wA0, wA1)
  }
#undef DGP
#undef LOADTAP

  // epilogue: D row = (lane>>4)*4 + reg (m), col = lane&15 (t); 8 t-tiles
  int lrow = lane & 15, lq = lane >> 4;
  int mbase = mhalf * 256 + wid * 64;
  float bvals[4][4];
#pragma unroll
  for (int i = 0; i < 4; ++i)
#pragma unroll
    for (int r = 0; r < 4; ++r) bvals[i][r] = bias[mbase + i * 16 + lq * 4 + r];
#pragma unroll
  for (int j = 0; j < 8; ++j) {
    int col = j * 16 + lrow;
    int t = tb + col;
    float mk = mask[(b << tsh) + t];
    if (OUT_BF16) {
      short* orow = (short*)outp + (((size_t)(b << tsh) + t) << 9);
#pragma unroll
      for (int i = 0; i < 4; ++i) {
        bf16x4 pv;
#pragma unroll
        for (int r = 0; r < 4; ++r)
          pv[r] = f2b(fmaxf(acc[i][j][r] + bvals[i][r], 0.f) * mk);
        *(bf16x4*)(orow + mbase + i * 16 + lq * 4) = pv;
      }
    } else {
#pragma unroll
      for (int i = 0; i < 4; ++i) {
        int m = mbase + i * 16 + lq * 4;
#pragma unroll
        for (int r = 0; r < 4; ++r) {
          float v = fmaxf(acc[i][j][r] + bvals[i][r], 0.f) * mk;
          ((float*)outp)[(((size_t)(b * 512 + m + r)) << tsh) + t] = v;
        }
      }
    }
  }
}

// ---------- launch ----------
extern "C" void kernel_launch(void* const* d_in, const int* in_sizes, int n_in, void* d_out,
                              int out_size, void* d_ws, size_t ws_size, hipStream_t stream) {
  const float* feats[3] = {(const float*)d_in[0], (const float*)d_in[3], (const float*)d_in[6]};
  const float* maskp[3] = {(const float*)d_in[1], (const float*)d_in[4], (const float*)d_in[7]};
  const float* offs[3] = {(const float*)d_in[2], (const float*)d_in[5], (const float*)d_in[8]};
  const float* w[2] = {(const float*)d_in[9], (const float*)d_in[13]};
  const float* bias[2] = {(const float*)d_in[10], (const float*)d_in[14]};
  const float* ow[2] = {(const float*)d_in[11], (const float*)d_in[15]};
  const float* ob[2] = {(const float*)d_in[12], (const float*)d_in[16]};

  const size_t YOFF[3] = {0, 8388608, 12582912};
  const size_t MOFF = 14680064;

  uint8_t* ws = (uint8_t*)d_ws;
  __hip_bfloat16* Wf0 = (__hip_bfloat16*)ws;                 // 1,572,864 B
  __hip_bfloat16* Wf1 = (__hip_bfloat16*)(ws + 1572864);     // 1,572,864 B
  __hip_bfloat16* owF1hi = (__hip_bfloat16*)(ws + 3145728);  // 49,152 B
  __hip_bfloat16* owF1lo = (__hip_bfloat16*)(ws + 3194880);  // 49,152 B
  float* P1 = (float*)(ws + 3244032);                        // 1,376,256 B
  float* offc2 = (float*)(ws + 4620288);                     // 344,064 B
  __hip_bfloat16* fT = (__hip_bfloat16*)(ws + 8388608);      // 29,360,128 B
  __hip_bfloat16* x1T = (__hip_bfloat16*)(ws + 37748736);    // 29,360,128 B (end 67,108,864)

  float* outf = (float*)d_out;

  setup_kernel<<<6448, 256, 0, stream>>>(w[0], w[1], Wf0, Wf1, ow[1], owF1hi, owF1lo,
                                         maskp[0], maskp[1], maskp[2], outf + MOFF);
  transpose_kernel<<<3584, 256, 0, stream>>>(feats[0], feats[1], feats[2], fT);
  offconv1_kernel<<<dim3(448, 4), 256, 0, stream>>>(feats[0], feats[1], feats[2], ow[0], P1);

  // layer 1
  dgemm_kernel<false, true><<<dim3(224, 2), 256, 0, stream>>>(
      fT, Wf0, offs[0], offs[1], offs[2], P1, offc2, ob[0], ob[1], bias[0],
      maskp[0], maskp[1], maskp[2], (void*)x1T, (void*)(x1T + YOFF[1]), (void*)(x1T + YOFF[2]));

  // layer 2
  offconv2_kernel<<<448, 256, 0, stream>>>(x1T, owF1hi, owF1lo, offc2);
  dgemm_kernel<true, false><<<dim3(224, 2), 256, 0, stream>>>(
      x1T, Wf1, offs[0], offs[1], offs[2], P1, offc2, ob[0], ob[1], bias[1],
      maskp[0], maskp[1], maskp[2], (void*)(outf + YOFF[0]), (void*)(outf + YOFF[1]),
      (void*)(outf + YOFF[2]));
}